// Round 3
// baseline (2291.730 us; speedup 1.0000x reference)
//
#include <hip/hip_runtime.h>
#include <hip/hip_cooperative_groups.h>

namespace cg = cooperative_groups;

#define TFULL 4092
#define NB    64
#define CH    16
#define OUT_T 2048
#define TOFF  2044   // TFULL - OUT_T; also ts[17]

// One thread owns one (b, t) for all 18 layers. Signal ping-pongs through
// global ws with grid.sync() between layers. Mixer output accumulates in a
// register. Own-row signal (k=2 tap) and own-row controls stay in registers.
__global__ __launch_bounds__(256, 4) void fused_wavenet(
    const float* __restrict__ input,    // (B, T, 4)
    const float* __restrict__ conv_w0,  // (3, 4, 16)
    const float* __restrict__ conv_w,   // (17, 3, 19, 16)
    const float* __restrict__ conv_b,   // (18, 16)
    const float* __restrict__ io_w,     // (17, 16, 16)
    const float* __restrict__ io_b,     // (17, 16)
    const float* __restrict__ mixer_w,  // (288, 1)
    const float* __restrict__ mixer_b,  // (1,)
    float* __restrict__ sigA,           // (B, T, 16) ws
    float* __restrict__ sigB,           // (B, T, 16) ws
    float* __restrict__ out)            // (B, 2048)
{
    cg::grid_group grid = cg::this_grid();

    const int b = blockIdx.y;
    const int t = blockIdx.x * 256 + threadIdx.x;
    const bool in_t   = (t < TFULL);
    const bool in_out = in_t && (t >= TOFF);

    const float* ib = input + (size_t)b * TFULL * 4;

    float out_acc = in_out ? mixer_b[0] : 0.f;

    // own input row (signal ch 0 + 3 controls), cached for all layers
    float csig = 0.f, cc2y = 0.f, cc2z = 0.f, cc2w = 0.f;
    if (in_t) {
        const float4 x = *(const float4*)(ib + (size_t)t * 4);
        csig = x.x; cc2y = x.y; cc2z = x.z; cc2w = x.w;
    }

    float sn[CH];   // own signal row for the NEXT layer (registers)

    // ---------------- layer 0: conv(4->16, d=1), t >= 2 (ts[0]=2) ----------------
    {
        const bool active = in_t && (t >= 2);
        if (active) {
            float h[CH];
            #pragma unroll
            for (int o = 0; o < CH; ++o) h[o] = conv_b[o];
            #pragma unroll
            for (int k = 0; k < 3; ++k) {
                const int tt = t - (2 - k);          // tt >= 0 guaranteed (t>=2)
                const float4 x = *(const float4*)(ib + (size_t)tt * 4);
                const float xv[4] = {x.x, x.y, x.z, x.w};
                #pragma unroll
                for (int c = 0; c < 4; ++c) {
                    #pragma unroll
                    for (int o = 0; o < CH; ++o)
                        h[o] = fmaf(xv[c], conv_w0[(k * 4 + c) * CH + o], h[o]);
                }
            }
            #pragma unroll
            for (int o = 0; o < CH; ++o) h[o] = fmaxf(h[o], 0.f);

            if (in_out) {
                #pragma unroll
                for (int o = 0; o < CH; ++o) out_acc = fmaf(h[o], mixer_w[o], out_acc);
            }
            // signal_1 = h @ io_w[0] + io_b[0] + signal_0/2  (signal_0 = input ch 0)
            const float half = csig * 0.5f;
            #pragma unroll
            for (int o = 0; o < CH; ++o) sn[o] = io_b[o] + half;
            #pragma unroll
            for (int c = 0; c < CH; ++c) {
                #pragma unroll
                for (int o = 0; o < CH; ++o)
                    sn[o] = fmaf(h[c], io_w[c * CH + o], sn[o]);
            }
            float* op = sigA + ((size_t)b * TFULL + t) * CH;
            *(float4*)(op + 0)  = make_float4(sn[0],  sn[1],  sn[2],  sn[3]);
            *(float4*)(op + 4)  = make_float4(sn[4],  sn[5],  sn[6],  sn[7]);
            *(float4*)(op + 8)  = make_float4(sn[8],  sn[9],  sn[10], sn[11]);
            *(float4*)(op + 12) = make_float4(sn[12], sn[13], sn[14], sn[15]);
        }
    }
    grid.sync();

    // ---------------- layers 1..17 ----------------
    const float* cur = sigA;
    float* nxt = sigB;
    int t0 = 2;                                  // ts[0]
    for (int i = 1; i < 18; ++i) {
        const int dil = 1 << (i % 9);            // 1,2,..,256,1,2,..,256
        t0 += 2 * dil;                           // ts[i] = ts[i-1] + 2*dil[i]
        const float* w  = conv_w  + (size_t)(i - 1) * 3 * 19 * CH;
        const float* bs = conv_b  + (size_t)i * CH;
        const float* mw = mixer_w + (size_t)i * CH;
        const bool active = in_t && (t >= t0);   // taps >= ts[i-1] >= 0

        if (active) {
            const float* sb = cur + (size_t)b * TFULL * CH;
            const int tt0 = t - 2 * dil;
            const int tt1 = t - dil;
            // issue all global loads for both far taps up front
            const float4* sp0 = (const float4*)(sb + (size_t)tt0 * CH);
            const float4* sp1 = (const float4*)(sb + (size_t)tt1 * CH);
            const float4 a0 = sp0[0], a1 = sp0[1], a2 = sp0[2], a3 = sp0[3];
            const float4 b0 = sp1[0], b1 = sp1[1], b2 = sp1[2], b3 = sp1[3];
            const float4 c0 = *(const float4*)(ib + (size_t)tt0 * 4);
            const float4 c1 = *(const float4*)(ib + (size_t)tt1 * 4);

            float h[CH];
            #pragma unroll
            for (int o = 0; o < CH; ++o) h[o] = bs[o];

            {   // k = 0 tap
                const float sv[CH] = {a0.x,a0.y,a0.z,a0.w, a1.x,a1.y,a1.z,a1.w,
                                      a2.x,a2.y,a2.z,a2.w, a3.x,a3.y,a3.z,a3.w};
                #pragma unroll
                for (int c = 0; c < CH; ++c) {
                    #pragma unroll
                    for (int o = 0; o < CH; ++o)
                        h[o] = fmaf(sv[c], w[(0 * 19 + c) * CH + o], h[o]);
                }
                const float cv[3] = {c0.y, c0.z, c0.w};
                #pragma unroll
                for (int c = 0; c < 3; ++c) {
                    #pragma unroll
                    for (int o = 0; o < CH; ++o)
                        h[o] = fmaf(cv[c], w[(0 * 19 + 16 + c) * CH + o], h[o]);
                }
            }
            {   // k = 1 tap
                const float sv[CH] = {b0.x,b0.y,b0.z,b0.w, b1.x,b1.y,b1.z,b1.w,
                                      b2.x,b2.y,b2.z,b2.w, b3.x,b3.y,b3.z,b3.w};
                #pragma unroll
                for (int c = 0; c < CH; ++c) {
                    #pragma unroll
                    for (int o = 0; o < CH; ++o)
                        h[o] = fmaf(sv[c], w[(1 * 19 + c) * CH + o], h[o]);
                }
                const float cv[3] = {c1.y, c1.z, c1.w};
                #pragma unroll
                for (int c = 0; c < 3; ++c) {
                    #pragma unroll
                    for (int o = 0; o < CH; ++o)
                        h[o] = fmaf(cv[c], w[(1 * 19 + 16 + c) * CH + o], h[o]);
                }
            }
            // k = 2 tap: own row from registers
            float sum_t = 0.f;
            #pragma unroll
            for (int c = 0; c < CH; ++c) {
                sum_t += sn[c];
                #pragma unroll
                for (int o = 0; o < CH; ++o)
                    h[o] = fmaf(sn[c], w[(2 * 19 + c) * CH + o], h[o]);
            }
            {
                const float cv[3] = {cc2y, cc2z, cc2w};
                #pragma unroll
                for (int c = 0; c < 3; ++c) {
                    #pragma unroll
                    for (int o = 0; o < CH; ++o)
                        h[o] = fmaf(cv[c], w[(2 * 19 + 16 + c) * CH + o], h[o]);
                }
            }
            #pragma unroll
            for (int o = 0; o < CH; ++o) h[o] = fmaxf(h[o], 0.f);

            if (in_out) {
                #pragma unroll
                for (int o = 0; o < CH; ++o) out_acc = fmaf(h[o], mw[o], out_acc);
            }

            if (i < 17) {
                const float* iw = io_w + (size_t)i * CH * CH;
                const float* ob = io_b + (size_t)i * CH;
                const float half = sum_t * 0.5f;
                #pragma unroll
                for (int o = 0; o < CH; ++o) sn[o] = ob[o] + half;   // sn's old value no longer needed
                #pragma unroll
                for (int c = 0; c < CH; ++c) {
                    #pragma unroll
                    for (int o = 0; o < CH; ++o)
                        sn[o] = fmaf(h[c], iw[c * CH + o], sn[o]);
                }
                float* op = nxt + ((size_t)b * TFULL + t) * CH;
                *(float4*)(op + 0)  = make_float4(sn[0],  sn[1],  sn[2],  sn[3]);
                *(float4*)(op + 4)  = make_float4(sn[4],  sn[5],  sn[6],  sn[7]);
                *(float4*)(op + 8)  = make_float4(sn[8],  sn[9],  sn[10], sn[11]);
                *(float4*)(op + 12) = make_float4(sn[12], sn[13], sn[14], sn[15]);
            }
        }
        if (i < 17) grid.sync();
        const float* tmp = cur; cur = nxt; nxt = (float*)tmp;
    }

    if (in_out) out[(size_t)b * OUT_T + (t - TOFF)] = out_acc;
}

extern "C" void kernel_launch(void* const* d_in, const int* in_sizes, int n_in,
                              void* d_out, int out_size, void* d_ws, size_t ws_size,
                              hipStream_t stream) {
    const float* input   = (const float*)d_in[0];
    const float* conv_w0 = (const float*)d_in[1];
    const float* conv_w  = (const float*)d_in[2];
    const float* conv_b  = (const float*)d_in[3];
    const float* io_w    = (const float*)d_in[4];
    const float* io_b    = (const float*)d_in[5];
    const float* mixer_w = (const float*)d_in[6];
    const float* mixer_b = (const float*)d_in[7];
    float* out = (float*)d_out;

    float* sigA = (float*)d_ws;
    float* sigB = sigA + (size_t)NB * TFULL * CH;

    // 16 blocks cover 4096 >= TFULL t-positions; grid = 1024 blocks = 4/CU,
    // guaranteed co-resident by __launch_bounds__(256, 4) (VGPR <= 128, LDS 0).
    dim3 grid(16, NB, 1);
    dim3 block(256, 1, 1);
    void* args[] = {(void*)&input, (void*)&conv_w0, (void*)&conv_w, (void*)&conv_b,
                    (void*)&io_w, (void*)&io_b, (void*)&mixer_w, (void*)&mixer_b,
                    (void*)&sigA, (void*)&sigB, (void*)&out};
    hipLaunchCooperativeKernel((void*)fused_wavenet, grid, block, args, 0, stream);
}

// Round 4
// 431.034 us; speedup vs baseline: 5.3168x; 5.3168x over previous
//
#include <hip/hip_runtime.h>

#define TFULL 4092
#define NB    64
#define CH    16
#define OUT_T 2048
#define TOFF  2044       // TFULL - OUT_T
#define NT    512        // threads per block (8 waves)
#define RSTRIDE 20       // floats per LDS row: [0..15] signal, [16..19] raw input float4

// Fused group of dilated-conv layers, LDS-resident, in-place update with
// descending-chunk two-phase discipline (reads of layer-input complete
// before writes of layer-output touch the same rows).
//
// L0: first global layer index; NL: #layers; TILE: main rows per tile;
// HALO: group receptive halo (= sum of 2*dil over group layers).
// Layer ranges: layer i computes rows [tile_lo - (HALO - cum_i), tile_hi),
// cum_i = sum_{j<=i} 2*dil_j; taps never go below buf_lo = tile_lo - HALO.
template<int L0, int NL, int TILE, int HALO, bool FIRSTG, bool LASTG>
__global__ __launch_bounds__(NT, 2) void group_kernel(
    const float* __restrict__ input,     // (B,T,4)
    const float* __restrict__ conv_w0,   // (3,4,16)
    const float* __restrict__ conv_w,    // (17,3,19,16)
    const float* __restrict__ conv_b,    // (18,16)
    const float* __restrict__ io_w,      // (17,16,16)
    const float* __restrict__ io_b,      // (17,16)
    const float* __restrict__ mixer_w,   // (288)
    const float* __restrict__ mixer_b,   // (1)
    const float* __restrict__ sig_in,    // prev group's signal (B,T,16); unused if FIRSTG
    float* __restrict__ sig_out,         // this group's out signal; unused if LASTG
    float* __restrict__ out,             // (B,2048)
    int out_start)                       // first main row of this group
{
    constexpr int NROWS = TILE + HALO;
    __shared__ float buf[NROWS * RSTRIDE];
    __shared__ float macc[TILE];         // per-main-row mixer accumulator

    const int b       = blockIdx.y;
    const int tile_lo = out_start + blockIdx.x * TILE;
    const int tile_hi = (tile_lo + TILE < TFULL) ? (tile_lo + TILE) : TFULL;
    const int buf_lo  = tile_lo - HALO;  // global row of LDS row 0 (always >= 0)
    const int tid     = threadIdx.x;

    // ---- stage in: raw input float4 -> slots[16..19]; prev signal -> [0..15] ----
    {
        const float* ib = input + ((size_t)b * TFULL + buf_lo) * 4;
        const int nstage = tile_hi - buf_lo;
        for (int j = tid; j < nstage; j += NT) {
            *(float4*)(&buf[j * RSTRIDE + 16]) = *(const float4*)(ib + (size_t)j * 4);
            if constexpr (!FIRSTG) {
                const float* sp = sig_in + ((size_t)b * TFULL + (buf_lo + j)) * CH;
                *(float4*)(&buf[j * RSTRIDE + 0])  = *(const float4*)(sp + 0);
                *(float4*)(&buf[j * RSTRIDE + 4])  = *(const float4*)(sp + 4);
                *(float4*)(&buf[j * RSTRIDE + 8])  = *(const float4*)(sp + 8);
                *(float4*)(&buf[j * RSTRIDE + 12]) = *(const float4*)(sp + 12);
            }
        }
        for (int j = tid; j < TILE; j += NT) macc[j] = 0.f;
    }
    __syncthreads();

    // ---- layer loop (rolled; body ~1.3k inst keeps I$ resident) ----
    int lo = buf_lo;
    for (int i = 0; i < NL; ++i) {
        const int g   = L0 + i;
        const int dil = 1 << (g % 9);          // 1,2,..,256,1,2,..,256
        lo += 2 * dil;                         // this layer computes [lo, tile_hi)
        const bool lastl = (i == NL - 1);      // (for last layer, lo == tile_lo)
        const float* wb   = (g == 0) ? conv_w0 : (conv_w + (size_t)(g - 1) * 3 * 19 * CH);
        const float* bias = conv_b  + (size_t)g * CH;
        const float* iw   = io_w    + (size_t)g * CH * CH;
        const float* iob2 = io_b    + (size_t)g * CH;
        const float* mw   = mixer_w + (size_t)g * CH;

        const int n   = tile_hi - lo;
        const int nch = (n + NT - 1) / NT;
        // chunks descend in t: a chunk's taps (<= own row) never touch rows
        // written by earlier (higher) chunks -> one sync between R and W.
        for (int c = 0; c < nch; ++c) {
            const int r   = tile_hi - (c + 1) * NT + tid;
            const bool act = (r >= lo);
            int j = 0;
            float sn[CH];
            if (act) {
                j = r - buf_lo;
                const float* r2 = &buf[j * RSTRIDE];             // k=2 tap (own row)
                const float* r1 = &buf[(j - dil) * RSTRIDE];     // k=1
                const float* r0 = &buf[(j - 2 * dil) * RSTRIDE]; // k=0

                float h[CH];
                #pragma unroll
                for (int o = 0; o < CH; ++o) h[o] = bias[o];
                float sum_t;

                if (FIRSTG && g == 0) {
                    // layer 0: 4-channel input conv, from slots[16..19]
                    const float4 x0 = *(const float4*)(r0 + 16);
                    const float4 x1 = *(const float4*)(r1 + 16);
                    const float4 x2 = *(const float4*)(r2 + 16);
                    const float t0[4] = {x0.x, x0.y, x0.z, x0.w};
                    const float t1[4] = {x1.x, x1.y, x1.z, x1.w};
                    const float t2[4] = {x2.x, x2.y, x2.z, x2.w};
                    #pragma unroll
                    for (int cc = 0; cc < 4; ++cc) {
                        #pragma unroll
                        for (int o = 0; o < CH; ++o) {
                            h[o] = fmaf(t0[cc], wb[(0 * 4 + cc) * CH + o], h[o]);
                            h[o] = fmaf(t1[cc], wb[(1 * 4 + cc) * CH + o], h[o]);
                            h[o] = fmaf(t2[cc], wb[(2 * 4 + cc) * CH + o], h[o]);
                        }
                    }
                    sum_t = x2.x;   // 1-channel signal sum = input ch0
                } else {
                    // 19-channel conv: 16 signal [0..15] + 3 controls [17..19]
                    const float4 a0 = *(const float4*)(r0 + 0),  a1 = *(const float4*)(r0 + 4),
                                 a2 = *(const float4*)(r0 + 8),  a3 = *(const float4*)(r0 + 12),
                                 a4 = *(const float4*)(r0 + 16);
                    const float4 b0 = *(const float4*)(r1 + 0),  b1 = *(const float4*)(r1 + 4),
                                 b2 = *(const float4*)(r1 + 8),  b3 = *(const float4*)(r1 + 12),
                                 b4 = *(const float4*)(r1 + 16);
                    const float4 c0 = *(const float4*)(r2 + 0),  c1 = *(const float4*)(r2 + 4),
                                 c2 = *(const float4*)(r2 + 8),  c3 = *(const float4*)(r2 + 12),
                                 c4 = *(const float4*)(r2 + 16);
                    const float t0[19] = {a0.x,a0.y,a0.z,a0.w, a1.x,a1.y,a1.z,a1.w,
                                          a2.x,a2.y,a2.z,a2.w, a3.x,a3.y,a3.z,a3.w,
                                          a4.y,a4.z,a4.w};
                    const float t1[19] = {b0.x,b0.y,b0.z,b0.w, b1.x,b1.y,b1.z,b1.w,
                                          b2.x,b2.y,b2.z,b2.w, b3.x,b3.y,b3.z,b3.w,
                                          b4.y,b4.z,b4.w};
                    const float t2[19] = {c0.x,c0.y,c0.z,c0.w, c1.x,c1.y,c1.z,c1.w,
                                          c2.x,c2.y,c2.z,c2.w, c3.x,c3.y,c3.z,c3.w,
                                          c4.y,c4.z,c4.w};
                    #pragma unroll
                    for (int cc = 0; cc < 19; ++cc) {
                        #pragma unroll
                        for (int o = 0; o < CH; ++o) {
                            h[o] = fmaf(t0[cc], wb[(0 * 19 + cc) * CH + o], h[o]);
                            h[o] = fmaf(t1[cc], wb[(1 * 19 + cc) * CH + o], h[o]);
                            h[o] = fmaf(t2[cc], wb[(2 * 19 + cc) * CH + o], h[o]);
                        }
                    }
                    sum_t = ((c0.x + c0.y) + (c0.z + c0.w)) + ((c1.x + c1.y) + (c1.z + c1.w))
                          + ((c2.x + c2.y) + (c2.z + c2.w)) + ((c3.x + c3.y) + (c3.z + c3.w));
                }
                #pragma unroll
                for (int o = 0; o < CH; ++o) h[o] = fmaxf(h[o], 0.f);

                // mixer: only main rows (halo rows are another tile's mains)
                if (r >= tile_lo && r >= TOFF) {
                    float m = 0.f;
                    #pragma unroll
                    for (int o = 0; o < CH; ++o) m = fmaf(h[o], mw[o], m);
                    macc[r - tile_lo] += m;
                }

                // io -> next signal (skip for global layer 17)
                if (!(LASTG && lastl)) {
                    const float half = 0.5f * sum_t;
                    #pragma unroll
                    for (int o = 0; o < CH; ++o) sn[o] = iob2[o] + half;
                    #pragma unroll
                    for (int cc = 0; cc < CH; ++cc) {
                        #pragma unroll
                        for (int o = 0; o < CH; ++o)
                            sn[o] = fmaf(h[cc], iw[cc * CH + o], sn[o]);
                    }
                }
            }
            __syncthreads();   // all reads of layer-input done before writes
            if (act) {
                if (!lastl) {
                    float* wp = &buf[j * RSTRIDE];
                    *(float4*)(wp + 0)  = make_float4(sn[0],  sn[1],  sn[2],  sn[3]);
                    *(float4*)(wp + 4)  = make_float4(sn[4],  sn[5],  sn[6],  sn[7]);
                    *(float4*)(wp + 8)  = make_float4(sn[8],  sn[9],  sn[10], sn[11]);
                    *(float4*)(wp + 12) = make_float4(sn[12], sn[13], sn[14], sn[15]);
                } else if (!LASTG) {
                    // last layer of group: write next-group signal to global (main rows)
                    float* gp = sig_out + ((size_t)b * TFULL + r) * CH;
                    *(float4*)(gp + 0)  = make_float4(sn[0],  sn[1],  sn[2],  sn[3]);
                    *(float4*)(gp + 4)  = make_float4(sn[4],  sn[5],  sn[6],  sn[7]);
                    *(float4*)(gp + 8)  = make_float4(sn[8],  sn[9],  sn[10], sn[11]);
                    *(float4*)(gp + 12) = make_float4(sn[12], sn[13], sn[14], sn[15]);
                }
            }
        }
        __syncthreads();       // layer boundary: all writes visible to next layer
    }

    // ---- flush mixer partials ----
    const int nmain = tile_hi - tile_lo;
    for (int j = tid; j < nmain; j += NT) {
        const int r = tile_lo + j;
        if (r >= TOFF) {
            const size_t oi = (size_t)b * OUT_T + (r - TOFF);
            if (FIRSTG) out[oi] = mixer_b[0] + macc[j];
            else        out[oi] += macc[j];
        }
    }
}

extern "C" void kernel_launch(void* const* d_in, const int* in_sizes, int n_in,
                              void* d_out, int out_size, void* d_ws, size_t ws_size,
                              hipStream_t stream) {
    const float* input   = (const float*)d_in[0];
    const float* conv_w0 = (const float*)d_in[1];
    const float* conv_w  = (const float*)d_in[2];
    const float* conv_b  = (const float*)d_in[3];
    const float* io_w    = (const float*)d_in[4];
    const float* io_b    = (const float*)d_in[5];
    const float* mixer_w = (const float*)d_in[6];
    const float* mixer_b = (const float*)d_in[7];
    float* out = (float*)d_out;

    float* sigA = (float*)d_ws;                      // signal_7  (B,T,16)
    float* sigB = sigA + (size_t)NB * TFULL * CH;    // signal_13 (B,T,16)

    dim3 block(NT, 1, 1);
    // G0: layers 0..6 (dil 1..64),  halo 254, out rows [254,4092),  4x1024 tiles
    group_kernel<0, 7, 1024, 254, true, false><<<dim3(4, NB), block, 0, stream>>>(
        input, conv_w0, conv_w, conv_b, io_w, io_b, mixer_w, mixer_b,
        nullptr, sigA, out, 254);
    // G1: layers 7..12 (dil 128,256,1,2,4,8), halo 798, out rows [1052,4092), 4x768
    group_kernel<7, 6, 768, 798, false, false><<<dim3(4, NB), block, 0, stream>>>(
        input, conv_w0, conv_w, conv_b, io_w, io_b, mixer_w, mixer_b,
        sigA, sigB, out, 1052);
    // G2: layers 13..17 (dil 16..256), halo 992, out rows [2044,4092), 4x512
    group_kernel<13, 5, 512, 992, false, true><<<dim3(4, NB), block, 0, stream>>>(
        input, conv_w0, conv_w, conv_b, io_w, io_b, mixer_w, mixer_b,
        sigB, nullptr, out, 2044);
}

// Round 5
// 334.464 us; speedup vs baseline: 6.8520x; 1.2887x over previous
//
#include <hip/hip_runtime.h>

#define TFULL 4092
#define NB    64
#define CH    16
#define OUT_T 2048
#define TOFF  2044       // TFULL - OUT_T
#define NT    512        // threads per block in fused kernels (8 waves)
#define RSTRIDE 20       // floats per LDS row: [0..15] signal, [16..19] raw input float4

// ---------------- fused group of layers, LDS-resident, in-place ----------------
// L0: first layer; NL: #layers; TILE: main rows/tile; HALO: sum 2*dil over group.
template<int L0, int NL, int TILE, int HALO, bool FIRSTG, bool LASTG>
__global__ __launch_bounds__(NT, 4) void group_kernel(
    const float* __restrict__ input,     // (B,T,4)
    const float* __restrict__ conv_w0,   // (3,4,16)
    const float* __restrict__ conv_w,    // (17,3,19,16)
    const float* __restrict__ conv_b,    // (18,16)
    const float* __restrict__ io_w,      // (17,16,16)
    const float* __restrict__ io_b,      // (17,16)
    const float* __restrict__ mixer_w,   // (288)
    const float* __restrict__ mixer_b,   // (1)
    const float* __restrict__ sig_in,    // prev signal (B,T,16); unused if FIRSTG
    float* __restrict__ sig_out,         // out signal; unused if LASTG
    float* __restrict__ out,             // (B,2048)
    int out_start)
{
    constexpr int NROWS = TILE + HALO;
    __shared__ float buf[NROWS * RSTRIDE];
    __shared__ float macc[TILE];

    const int b       = blockIdx.y;
    const int tile_lo = out_start + blockIdx.x * TILE;
    const int tile_hi = (tile_lo + TILE < TFULL) ? (tile_lo + TILE) : TFULL;
    const int buf_lo  = tile_lo - HALO;
    const int tid     = threadIdx.x;

    {   // stage in
        const float* ib = input + ((size_t)b * TFULL + buf_lo) * 4;
        const int nstage = tile_hi - buf_lo;
        for (int j = tid; j < nstage; j += NT) {
            *(float4*)(&buf[j * RSTRIDE + 16]) = *(const float4*)(ib + (size_t)j * 4);
            if constexpr (!FIRSTG) {
                const float* sp = sig_in + ((size_t)b * TFULL + (buf_lo + j)) * CH;
                *(float4*)(&buf[j * RSTRIDE + 0])  = *(const float4*)(sp + 0);
                *(float4*)(&buf[j * RSTRIDE + 4])  = *(const float4*)(sp + 4);
                *(float4*)(&buf[j * RSTRIDE + 8])  = *(const float4*)(sp + 8);
                *(float4*)(&buf[j * RSTRIDE + 12]) = *(const float4*)(sp + 12);
            }
        }
        for (int j = tid; j < TILE; j += NT) macc[j] = 0.f;
    }
    __syncthreads();

    int lo = buf_lo;
    for (int i = 0; i < NL; ++i) {
        const int g   = L0 + i;
        const int dil = 1 << (g % 9);
        lo += 2 * dil;
        const bool lastl = (i == NL - 1);
        const float* wb   = (FIRSTG && g == 0) ? conv_w0 : (conv_w + (size_t)(g - 1) * 3 * 19 * CH);
        const float* bias = conv_b  + (size_t)g * CH;
        const float* iw   = io_w    + (size_t)g * CH * CH;
        const float* iob2 = io_b    + (size_t)g * CH;
        const float* mw   = mixer_w + (size_t)g * CH;

        const int n   = tile_hi - lo;
        const int nch = (n + NT - 1) / NT;
        // descending chunks: a chunk's reads (rows <= own) never hit rows a
        // previous (higher) chunk wrote.
        for (int c = 0; c < nch; ++c) {
            const int r   = tile_hi - (c + 1) * NT + tid;
            const bool act = (r >= lo);
            int j = 0;
            float sn[CH];
            if (act) {
                j = r - buf_lo;
                const float* r2 = &buf[j * RSTRIDE];
                const float* r1 = &buf[(j - dil) * RSTRIDE];
                const float* r0 = &buf[(j - 2 * dil) * RSTRIDE];

                float h[CH];
                #pragma unroll
                for (int o = 0; o < CH; ++o) h[o] = bias[o];
                float sum_t;

                if (FIRSTG && g == 0) {
                    const float4 x0 = *(const float4*)(r0 + 16);
                    const float4 x1 = *(const float4*)(r1 + 16);
                    const float4 x2 = *(const float4*)(r2 + 16);
                    const float t0[4] = {x0.x, x0.y, x0.z, x0.w};
                    const float t1[4] = {x1.x, x1.y, x1.z, x1.w};
                    const float t2[4] = {x2.x, x2.y, x2.z, x2.w};
                    #pragma unroll
                    for (int cc = 0; cc < 4; ++cc) {
                        #pragma unroll
                        for (int o = 0; o < CH; ++o) {
                            h[o] = fmaf(t0[cc], wb[(0 * 4 + cc) * CH + o], h[o]);
                            h[o] = fmaf(t1[cc], wb[(1 * 4 + cc) * CH + o], h[o]);
                            h[o] = fmaf(t2[cc], wb[(2 * 4 + cc) * CH + o], h[o]);
                        }
                    }
                    sum_t = x2.x;
                } else {
                    const float4 a0 = *(const float4*)(r0 + 0),  a1 = *(const float4*)(r0 + 4),
                                 a2 = *(const float4*)(r0 + 8),  a3 = *(const float4*)(r0 + 12),
                                 a4 = *(const float4*)(r0 + 16);
                    const float4 b0 = *(const float4*)(r1 + 0),  b1 = *(const float4*)(r1 + 4),
                                 b2 = *(const float4*)(r1 + 8),  b3 = *(const float4*)(r1 + 12),
                                 b4 = *(const float4*)(r1 + 16);
                    const float4 c0 = *(const float4*)(r2 + 0),  c1 = *(const float4*)(r2 + 4),
                                 c2 = *(const float4*)(r2 + 8),  c3 = *(const float4*)(r2 + 12),
                                 c4 = *(const float4*)(r2 + 16);
                    const float t0[19] = {a0.x,a0.y,a0.z,a0.w, a1.x,a1.y,a1.z,a1.w,
                                          a2.x,a2.y,a2.z,a2.w, a3.x,a3.y,a3.z,a3.w,
                                          a4.y,a4.z,a4.w};
                    const float t1[19] = {b0.x,b0.y,b0.z,b0.w, b1.x,b1.y,b1.z,b1.w,
                                          b2.x,b2.y,b2.z,b2.w, b3.x,b3.y,b3.z,b3.w,
                                          b4.y,b4.z,b4.w};
                    const float t2[19] = {c0.x,c0.y,c0.z,c0.w, c1.x,c1.y,c1.z,c1.w,
                                          c2.x,c2.y,c2.z,c2.w, c3.x,c3.y,c3.z,c3.w,
                                          c4.y,c4.z,c4.w};
                    #pragma unroll
                    for (int cc = 0; cc < 19; ++cc) {
                        #pragma unroll
                        for (int o = 0; o < CH; ++o) {
                            h[o] = fmaf(t0[cc], wb[(0 * 19 + cc) * CH + o], h[o]);
                            h[o] = fmaf(t1[cc], wb[(1 * 19 + cc) * CH + o], h[o]);
                            h[o] = fmaf(t2[cc], wb[(2 * 19 + cc) * CH + o], h[o]);
                        }
                    }
                    sum_t = ((c0.x + c0.y) + (c0.z + c0.w)) + ((c1.x + c1.y) + (c1.z + c1.w))
                          + ((c2.x + c2.y) + (c2.z + c2.w)) + ((c3.x + c3.y) + (c3.z + c3.w));
                }
                #pragma unroll
                for (int o = 0; o < CH; ++o) h[o] = fmaxf(h[o], 0.f);

                if (r >= tile_lo && r >= TOFF) {
                    float m = 0.f;
                    #pragma unroll
                    for (int o = 0; o < CH; ++o) m = fmaf(h[o], mw[o], m);
                    macc[r - tile_lo] += m;
                }

                if (!(LASTG && lastl)) {
                    const float half = 0.5f * sum_t;
                    #pragma unroll
                    for (int o = 0; o < CH; ++o) sn[o] = iob2[o] + half;
                    #pragma unroll
                    for (int cc = 0; cc < CH; ++cc) {
                        #pragma unroll
                        for (int o = 0; o < CH; ++o)
                            sn[o] = fmaf(h[cc], iw[cc * CH + o], sn[o]);
                    }
                }
            }
            __syncthreads();
            if (act) {
                if (!lastl) {
                    float* wp = &buf[j * RSTRIDE];
                    *(float4*)(wp + 0)  = make_float4(sn[0],  sn[1],  sn[2],  sn[3]);
                    *(float4*)(wp + 4)  = make_float4(sn[4],  sn[5],  sn[6],  sn[7]);
                    *(float4*)(wp + 8)  = make_float4(sn[8],  sn[9],  sn[10], sn[11]);
                    *(float4*)(wp + 12) = make_float4(sn[12], sn[13], sn[14], sn[15]);
                } else if (!LASTG) {
                    float* gp = sig_out + ((size_t)b * TFULL + r) * CH;
                    *(float4*)(gp + 0)  = make_float4(sn[0],  sn[1],  sn[2],  sn[3]);
                    *(float4*)(gp + 4)  = make_float4(sn[4],  sn[5],  sn[6],  sn[7]);
                    *(float4*)(gp + 8)  = make_float4(sn[8],  sn[9],  sn[10], sn[11]);
                    *(float4*)(gp + 12) = make_float4(sn[12], sn[13], sn[14], sn[15]);
                }
            }
        }
        __syncthreads();
    }

    const int nmain = tile_hi - tile_lo;
    for (int j = tid; j < nmain; j += NT) {
        const int r = tile_lo + j;
        if (r >= TOFF) {
            const size_t oi = (size_t)b * OUT_T + (r - TOFF);
            if (FIRSTG) out[oi] = mixer_b[0] + macc[j];
            else        out[oi] += macc[j];
        }
    }
}

// ---------------- unfused single layer (big dilation, zero halo) ----------------
template<bool LASTL>
__global__ __launch_bounds__(256, 4) void single_layer(
    const float* __restrict__ input,    // (B,T,4)
    const float* __restrict__ sig_in,   // (B,T,16)
    const float* __restrict__ w,        // (3,19,16)
    const float* __restrict__ bias,     // (16)
    const float* __restrict__ iw,       // (16,16)   unused if LASTL
    const float* __restrict__ iob,      // (16)      unused if LASTL
    const float* __restrict__ mw,       // (16)
    float* __restrict__ sig_out,        // (B,T,16)  unused if LASTL
    float* __restrict__ out,            // (B,2048)
    int dil, int t0)
{
    const int b = blockIdx.y;
    const int t = t0 + blockIdx.x * 256 + threadIdx.x;
    if (t >= TFULL) return;
    const float* ib = input  + (size_t)b * TFULL * 4;
    const float* sb = sig_in + (size_t)b * TFULL * CH;

    const int tt0 = t - 2 * dil, tt1 = t - dil;   // always >= previous layer's t0
    // issue all loads up front
    const float4* sp0 = (const float4*)(sb + (size_t)tt0 * CH);
    const float4* sp1 = (const float4*)(sb + (size_t)tt1 * CH);
    const float4* sp2 = (const float4*)(sb + (size_t)t   * CH);
    const float4 a0 = sp0[0], a1 = sp0[1], a2 = sp0[2], a3 = sp0[3];
    const float4 b0 = sp1[0], b1 = sp1[1], b2 = sp1[2], b3 = sp1[3];
    const float4 c0 = sp2[0], c1 = sp2[1], c2 = sp2[2], c3 = sp2[3];
    const float4 x0 = *(const float4*)(ib + (size_t)tt0 * 4);
    const float4 x1 = *(const float4*)(ib + (size_t)tt1 * 4);
    const float4 x2 = *(const float4*)(ib + (size_t)t   * 4);

    float h[CH];
    #pragma unroll
    for (int o = 0; o < CH; ++o) h[o] = bias[o];

    const float t0v[19] = {a0.x,a0.y,a0.z,a0.w, a1.x,a1.y,a1.z,a1.w,
                           a2.x,a2.y,a2.z,a2.w, a3.x,a3.y,a3.z,a3.w,
                           x0.y,x0.z,x0.w};
    const float t1v[19] = {b0.x,b0.y,b0.z,b0.w, b1.x,b1.y,b1.z,b1.w,
                           b2.x,b2.y,b2.z,b2.w, b3.x,b3.y,b3.z,b3.w,
                           x1.y,x1.z,x1.w};
    const float t2v[19] = {c0.x,c0.y,c0.z,c0.w, c1.x,c1.y,c1.z,c1.w,
                           c2.x,c2.y,c2.z,c2.w, c3.x,c3.y,c3.z,c3.w,
                           x2.y,x2.z,x2.w};
    #pragma unroll
    for (int cc = 0; cc < 19; ++cc) {
        #pragma unroll
        for (int o = 0; o < CH; ++o) {
            h[o] = fmaf(t0v[cc], w[(0 * 19 + cc) * CH + o], h[o]);
            h[o] = fmaf(t1v[cc], w[(1 * 19 + cc) * CH + o], h[o]);
            h[o] = fmaf(t2v[cc], w[(2 * 19 + cc) * CH + o], h[o]);
        }
    }
    #pragma unroll
    for (int o = 0; o < CH; ++o) h[o] = fmaxf(h[o], 0.f);

    if (t >= TOFF) {
        float m = 0.f;
        #pragma unroll
        for (int o = 0; o < CH; ++o) m = fmaf(h[o], mw[o], m);
        out[(size_t)b * OUT_T + (t - TOFF)] += m;
    }

    if constexpr (!LASTL) {
        const float sum_t = ((c0.x + c0.y) + (c0.z + c0.w)) + ((c1.x + c1.y) + (c1.z + c1.w))
                          + ((c2.x + c2.y) + (c2.z + c2.w)) + ((c3.x + c3.y) + (c3.z + c3.w));
        float sn[CH];
        const float half = 0.5f * sum_t;
        #pragma unroll
        for (int o = 0; o < CH; ++o) sn[o] = iob[o] + half;
        #pragma unroll
        for (int cc = 0; cc < CH; ++cc) {
            #pragma unroll
            for (int o = 0; o < CH; ++o)
                sn[o] = fmaf(h[cc], iw[cc * CH + o], sn[o]);
        }
        float* gp = sig_out + ((size_t)b * TFULL + t) * CH;
        *(float4*)(gp + 0)  = make_float4(sn[0],  sn[1],  sn[2],  sn[3]);
        *(float4*)(gp + 4)  = make_float4(sn[4],  sn[5],  sn[6],  sn[7]);
        *(float4*)(gp + 8)  = make_float4(sn[8],  sn[9],  sn[10], sn[11]);
        *(float4*)(gp + 12) = make_float4(sn[12], sn[13], sn[14], sn[15]);
    }
}

extern "C" void kernel_launch(void* const* d_in, const int* in_sizes, int n_in,
                              void* d_out, int out_size, void* d_ws, size_t ws_size,
                              hipStream_t stream) {
    const float* input   = (const float*)d_in[0];
    const float* conv_w0 = (const float*)d_in[1];
    const float* conv_w  = (const float*)d_in[2];
    const float* conv_b  = (const float*)d_in[3];
    const float* io_w    = (const float*)d_in[4];
    const float* io_b    = (const float*)d_in[5];
    const float* mixer_w = (const float*)d_in[6];
    const float* mixer_b = (const float*)d_in[7];
    float* out = (float*)d_out;

    float* s1 = (float*)d_ws;
    float* s2 = s1 + (size_t)NB * TFULL * CH;

    auto wl  = [&](int g) { return conv_w + (size_t)(g - 1) * 3 * 19 * CH; };
    auto bsl = [&](int g) { return conv_b + (size_t)g * CH; };
    auto iwl = [&](int g) { return io_w + (size_t)g * CH * CH; };
    auto ibl = [&](int g) { return io_b + (size_t)g * CH; };
    auto mwl = [&](int g) { return mixer_w + (size_t)g * CH; };

    dim3 blk512(NT, 1, 1), blk256(256, 1, 1);

    // G_A: layers 0..6 (dil 1..64), halo 254, TILE 480, mains [254,4092), 8 tiles
    group_kernel<0, 7, 480, 254, true, false><<<dim3(8, NB), blk512, 0, stream>>>(
        input, conv_w0, conv_w, conv_b, io_w, io_b, mixer_w, mixer_b,
        nullptr, s1, out, 254);
    // L7 (dil 128): rows [510,4092) = 3582 -> 14 blocks/b ; s1 -> s2
    single_layer<false><<<dim3(14, NB), blk256, 0, stream>>>(
        input, s1, wl(7), bsl(7), iwl(7), ibl(7), mwl(7), s2, out, 128, 510);
    // L8 (dil 256): rows [1022,4092) = 3070 -> 12 ; s2 -> s1
    single_layer<false><<<dim3(12, NB), blk256, 0, stream>>>(
        input, s2, wl(8), bsl(8), iwl(8), ibl(8), mwl(8), s1, out, 256, 1022);
    // G_D: layers 9..14 (dil 1..32), halo 126, TILE 368, mains [1148,4092), 8 tiles ; s1 -> s2
    group_kernel<9, 6, 368, 126, false, false><<<dim3(8, NB), blk512, 0, stream>>>(
        input, conv_w0, conv_w, conv_b, io_w, io_b, mixer_w, mixer_b,
        s1, s2, out, 1148);
    // L15 (dil 64): rows [1276,4092) = 2816 -> 11 ; s2 -> s1
    single_layer<false><<<dim3(11, NB), blk256, 0, stream>>>(
        input, s2, wl(15), bsl(15), iwl(15), ibl(15), mwl(15), s1, out, 64, 1276);
    // L16 (dil 128): rows [1532,4092) = 2560 -> 10 ; s1 -> s2
    single_layer<false><<<dim3(10, NB), blk256, 0, stream>>>(
        input, s1, wl(16), bsl(16), iwl(16), ibl(16), mwl(16), s2, out, 128, 1532);
    // L17 (dil 256): rows [2044,4092) = 2048 -> 8 ; s2 -> out only
    single_layer<true><<<dim3(8, NB), blk256, 0, stream>>>(
        input, s2, wl(17), bsl(17), nullptr, nullptr, mwl(17), nullptr, out, 256, 2044);
}

// Round 6
// 306.274 us; speedup vs baseline: 7.4826x; 1.0920x over previous
//
#include <hip/hip_runtime.h>

#define TFULL 4092
#define NB    64
#define CH    16
#define OUT_T 2048
#define TOFF  2044       // TFULL - OUT_T
#define GNT   512        // threads per fused block (8 waves)

// ---------------- fused group, SoA-LDS, 2 rows/thread, register mixer acc ----------------
// Thread owns buffer rows j0 = NROWS-1024+tid and j1 = j0+512, FIXED across layers.
// Per layer: rows [lo_off, jmax) are recomputed in place (read all -> barrier ->
// write all -> barrier). Last group layer writes signal to global (mains only).
template<int L0, int NL, int TILE, int HALO, bool FIRSTG>
__global__ __launch_bounds__(GNT, 4) void group2_kernel(
    const float* __restrict__ input,     // (B,T,4)
    const float* __restrict__ conv_w0,   // (3,4,16)
    const float* __restrict__ conv_w,    // (17,3,19,16)
    const float* __restrict__ conv_b,    // (18,16)
    const float* __restrict__ io_w,      // (17,16,16)
    const float* __restrict__ io_b,      // (17,16)
    const float* __restrict__ mixer_w,   // (288)
    const float* __restrict__ mixer_b,   // (1)
    const float* __restrict__ sig_in,    // prev signal (B,T,16); unused if FIRSTG
    float* __restrict__ sig_out,         // group output signal (B,T,16)
    float* __restrict__ out,             // (B,2048)
    int out_start)
{
    constexpr int NROWS = TILE + HALO;
    __shared__ float4 buf4[4][NROWS];
    float4* pl0 = buf4[0]; float4* pl1 = buf4[1];
    float4* pl2 = buf4[2]; float4* pl3 = buf4[3];

    const int b       = blockIdx.y;
    const int tid     = threadIdx.x;
    const int tile_lo = out_start + blockIdx.x * TILE;
    const int tile_hi = (tile_lo + TILE < TFULL) ? (tile_lo + TILE) : TFULL;
    const int buf_lo  = tile_lo - HALO;
    const int jmax    = tile_hi - buf_lo;       // valid buffer rows: [0, jmax)
    const int j0      = NROWS - 1024 + tid;     // may be negative -> inactive
    const int j1      = NROWS - 512 + tid;      // always in [NROWS-512, NROWS)

    const float4* ib4 = (const float4*)(input + (size_t)b * TFULL * 4);

    if constexpr (!FIRSTG) {                    // stage signal planes
        const float* sp = sig_in + (size_t)b * TFULL * CH;
        for (int j = tid; j < jmax; j += GNT) {
            const float4* row = (const float4*)(sp + (size_t)(buf_lo + j) * CH);
            pl0[j] = row[0]; pl1[j] = row[1]; pl2[j] = row[2]; pl3[j] = row[3];
        }
        __syncthreads();
    }

    float acc0 = 0.f, acc1 = 0.f;
    int lo_off = 0;
    for (int i = 0; i < NL; ++i) {
        const int g   = L0 + i;
        const int dil = 1 << (g % 9);
        lo_off += 2 * dil;
        const bool lastl = (i == NL - 1);
        const float* wb   = (FIRSTG && g == 0) ? conv_w0
                                               : conv_w + (size_t)(g - 1) * 3 * 19 * CH;
        const float* bias = conv_b  + (size_t)g * CH;
        const float* iw   = io_w    + (size_t)g * CH * CH;
        const float* ob   = io_b    + (size_t)g * CH;
        const float* mw   = mixer_w + (size_t)g * CH;

        const bool a0 = (j0 >= lo_off) && (j0 < jmax);
        const bool a1 = (j1 >= lo_off) && (j1 < jmax);

        float sn0[CH], sn1[CH];

        auto row_compute = [&](int j, float* sn, float& accr) {
            float h[CH];
            #pragma unroll
            for (int o = 0; o < CH; ++o) h[o] = bias[o];
            float sum;
            if (FIRSTG && g == 0) {
                const float4 x0 = ib4[buf_lo + j - 2];
                const float4 x1 = ib4[buf_lo + j - 1];
                const float4 x2 = ib4[buf_lo + j];
                const float t0[4] = {x0.x, x0.y, x0.z, x0.w};
                const float t1[4] = {x1.x, x1.y, x1.z, x1.w};
                const float t2[4] = {x2.x, x2.y, x2.z, x2.w};
                #pragma unroll
                for (int cc = 0; cc < 4; ++cc) {
                    #pragma unroll
                    for (int o = 0; o < CH; ++o) {
                        h[o] = fmaf(t0[cc], wb[(0 * 4 + cc) * CH + o], h[o]);
                        h[o] = fmaf(t1[cc], wb[(1 * 4 + cc) * CH + o], h[o]);
                        h[o] = fmaf(t2[cc], wb[(2 * 4 + cc) * CH + o], h[o]);
                    }
                }
                sum = x2.x;
            } else {
                sum = 0.f;
                #pragma unroll
                for (int k = 0; k < 3; ++k) {
                    const int jm = j - (2 - k) * dil;
                    const float4 s0 = pl0[jm], s1v = pl1[jm],
                                 s2v = pl2[jm], s3v = pl3[jm];
                    const float4 x  = ib4[buf_lo + jm];
                    const float tv[19] = {s0.x, s0.y, s0.z, s0.w,
                                          s1v.x, s1v.y, s1v.z, s1v.w,
                                          s2v.x, s2v.y, s2v.z, s2v.w,
                                          s3v.x, s3v.y, s3v.z, s3v.w,
                                          x.y, x.z, x.w};
                    if (k == 2)
                        sum = ((s0.x + s0.y) + (s0.z + s0.w))
                            + ((s1v.x + s1v.y) + (s1v.z + s1v.w))
                            + ((s2v.x + s2v.y) + (s2v.z + s2v.w))
                            + ((s3v.x + s3v.y) + (s3v.z + s3v.w));
                    #pragma unroll
                    for (int cc = 0; cc < 19; ++cc) {
                        #pragma unroll
                        for (int o = 0; o < CH; ++o)
                            h[o] = fmaf(tv[cc], wb[(k * 19 + cc) * CH + o], h[o]);
                    }
                }
            }
            #pragma unroll
            for (int o = 0; o < CH; ++o) h[o] = fmaxf(h[o], 0.f);

            const int r = buf_lo + j;
            if (j >= HALO && r >= TOFF) {        // mixer: mains only
                float d = 0.f;
                #pragma unroll
                for (int o = 0; o < CH; ++o) d = fmaf(h[o], mw[o], d);
                accr += d;
            }
            const float half = 0.5f * sum;        // io -> next signal
            #pragma unroll
            for (int o = 0; o < CH; ++o) sn[o] = ob[o] + half;
            #pragma unroll
            for (int cc = 0; cc < CH; ++cc) {
                #pragma unroll
                for (int o = 0; o < CH; ++o)
                    sn[o] = fmaf(h[cc], iw[cc * CH + o], sn[o]);
            }
        };

        if (a0) row_compute(j0, sn0, acc0);
        if (a1) row_compute(j1, sn1, acc1);

        if (!lastl) {
            __syncthreads();                      // all LDS reads done
            if (a0) {
                pl0[j0] = make_float4(sn0[0],  sn0[1],  sn0[2],  sn0[3]);
                pl1[j0] = make_float4(sn0[4],  sn0[5],  sn0[6],  sn0[7]);
                pl2[j0] = make_float4(sn0[8],  sn0[9],  sn0[10], sn0[11]);
                pl3[j0] = make_float4(sn0[12], sn0[13], sn0[14], sn0[15]);
            }
            if (a1) {
                pl0[j1] = make_float4(sn1[0],  sn1[1],  sn1[2],  sn1[3]);
                pl1[j1] = make_float4(sn1[4],  sn1[5],  sn1[6],  sn1[7]);
                pl2[j1] = make_float4(sn1[8],  sn1[9],  sn1[10], sn1[11]);
                pl3[j1] = make_float4(sn1[12], sn1[13], sn1[14], sn1[15]);
            }
            __syncthreads();                      // writes visible to next layer
        } else {
            // last group layer: lo_off == HALO -> active rows are exactly mains.
            if (a0) {
                float* gp = sig_out + ((size_t)b * TFULL + (buf_lo + j0)) * CH;
                *(float4*)(gp + 0)  = make_float4(sn0[0],  sn0[1],  sn0[2],  sn0[3]);
                *(float4*)(gp + 4)  = make_float4(sn0[4],  sn0[5],  sn0[6],  sn0[7]);
                *(float4*)(gp + 8)  = make_float4(sn0[8],  sn0[9],  sn0[10], sn0[11]);
                *(float4*)(gp + 12) = make_float4(sn0[12], sn0[13], sn0[14], sn0[15]);
            }
            if (a1) {
                float* gp = sig_out + ((size_t)b * TFULL + (buf_lo + j1)) * CH;
                *(float4*)(gp + 0)  = make_float4(sn1[0],  sn1[1],  sn1[2],  sn1[3]);
                *(float4*)(gp + 4)  = make_float4(sn1[4],  sn1[5],  sn1[6],  sn1[7]);
                *(float4*)(gp + 8)  = make_float4(sn1[8],  sn1[9],  sn1[10], sn1[11]);
                *(float4*)(gp + 12) = make_float4(sn1[12], sn1[13], sn1[14], sn1[15]);
            }
        }
    }

    // epilogue: mixer partials (register) -> out
    if (j0 >= HALO && j0 < jmax) {
        const int r = buf_lo + j0;
        if (r >= TOFF) {
            const size_t oi = (size_t)b * OUT_T + (r - TOFF);
            if constexpr (FIRSTG) out[oi] = mixer_b[0] + acc0; else out[oi] += acc0;
        }
    }
    if (j1 >= HALO && j1 < jmax) {
        const int r = buf_lo + j1;
        if (r >= TOFF) {
            const size_t oi = (size_t)b * OUT_T + (r - TOFF);
            if constexpr (FIRSTG) out[oi] = mixer_b[0] + acc1; else out[oi] += acc1;
        }
    }
}

// ---------------- unfused single layer (big dilation, zero halo) ----------------
template<bool LASTL>
__global__ __launch_bounds__(256, 4) void single_layer(
    const float* __restrict__ input,    // (B,T,4)
    const float* __restrict__ sig_in,   // (B,T,16)
    const float* __restrict__ w,        // (3,19,16)
    const float* __restrict__ bias,     // (16)
    const float* __restrict__ iw,       // (16,16)   unused if LASTL
    const float* __restrict__ iob,      // (16)      unused if LASTL
    const float* __restrict__ mw,       // (16)
    float* __restrict__ sig_out,        // (B,T,16)  unused if LASTL
    float* __restrict__ out,            // (B,2048)
    int dil, int t0)
{
    const int b = blockIdx.y;
    const int t = t0 + blockIdx.x * 256 + threadIdx.x;
    if (t >= TFULL) return;
    const float* ib = input  + (size_t)b * TFULL * 4;
    const float* sb = sig_in + (size_t)b * TFULL * CH;

    const int tt0 = t - 2 * dil, tt1 = t - dil;
    const float4* sp0 = (const float4*)(sb + (size_t)tt0 * CH);
    const float4* sp1 = (const float4*)(sb + (size_t)tt1 * CH);
    const float4* sp2 = (const float4*)(sb + (size_t)t   * CH);
    const float4 a0 = sp0[0], a1 = sp0[1], a2 = sp0[2], a3 = sp0[3];
    const float4 b0 = sp1[0], b1 = sp1[1], b2 = sp1[2], b3 = sp1[3];
    const float4 c0 = sp2[0], c1 = sp2[1], c2 = sp2[2], c3 = sp2[3];
    const float4 x0 = *(const float4*)(ib + (size_t)tt0 * 4);
    const float4 x1 = *(const float4*)(ib + (size_t)tt1 * 4);
    const float4 x2 = *(const float4*)(ib + (size_t)t   * 4);

    float h[CH];
    #pragma unroll
    for (int o = 0; o < CH; ++o) h[o] = bias[o];

    const float t0v[19] = {a0.x,a0.y,a0.z,a0.w, a1.x,a1.y,a1.z,a1.w,
                           a2.x,a2.y,a2.z,a2.w, a3.x,a3.y,a3.z,a3.w,
                           x0.y,x0.z,x0.w};
    const float t1v[19] = {b0.x,b0.y,b0.z,b0.w, b1.x,b1.y,b1.z,b1.w,
                           b2.x,b2.y,b2.z,b2.w, b3.x,b3.y,b3.z,b3.w,
                           x1.y,x1.z,x1.w};
    const float t2v[19] = {c0.x,c0.y,c0.z,c0.w, c1.x,c1.y,c1.z,c1.w,
                           c2.x,c2.y,c2.z,c2.w, c3.x,c3.y,c3.z,c3.w,
                           x2.y,x2.z,x2.w};
    #pragma unroll
    for (int cc = 0; cc < 19; ++cc) {
        #pragma unroll
        for (int o = 0; o < CH; ++o) {
            h[o] = fmaf(t0v[cc], w[(0 * 19 + cc) * CH + o], h[o]);
            h[o] = fmaf(t1v[cc], w[(1 * 19 + cc) * CH + o], h[o]);
            h[o] = fmaf(t2v[cc], w[(2 * 19 + cc) * CH + o], h[o]);
        }
    }
    #pragma unroll
    for (int o = 0; o < CH; ++o) h[o] = fmaxf(h[o], 0.f);

    if (t >= TOFF) {
        float m = 0.f;
        #pragma unroll
        for (int o = 0; o < CH; ++o) m = fmaf(h[o], mw[o], m);
        out[(size_t)b * OUT_T + (t - TOFF)] += m;
    }

    if constexpr (!LASTL) {
        const float sum_t = ((c0.x + c0.y) + (c0.z + c0.w)) + ((c1.x + c1.y) + (c1.z + c1.w))
                          + ((c2.x + c2.y) + (c2.z + c2.w)) + ((c3.x + c3.y) + (c3.z + c3.w));
        float sn[CH];
        const float half = 0.5f * sum_t;
        #pragma unroll
        for (int o = 0; o < CH; ++o) sn[o] = iob[o] + half;
        #pragma unroll
        for (int cc = 0; cc < CH; ++cc) {
            #pragma unroll
            for (int o = 0; o < CH; ++o)
                sn[o] = fmaf(h[cc], iw[cc * CH + o], sn[o]);
        }
        float* gp = sig_out + ((size_t)b * TFULL + t) * CH;
        *(float4*)(gp + 0)  = make_float4(sn[0],  sn[1],  sn[2],  sn[3]);
        *(float4*)(gp + 4)  = make_float4(sn[4],  sn[5],  sn[6],  sn[7]);
        *(float4*)(gp + 8)  = make_float4(sn[8],  sn[9],  sn[10], sn[11]);
        *(float4*)(gp + 12) = make_float4(sn[12], sn[13], sn[14], sn[15]);
    }
}

extern "C" void kernel_launch(void* const* d_in, const int* in_sizes, int n_in,
                              void* d_out, int out_size, void* d_ws, size_t ws_size,
                              hipStream_t stream) {
    const float* input   = (const float*)d_in[0];
    const float* conv_w0 = (const float*)d_in[1];
    const float* conv_w  = (const float*)d_in[2];
    const float* conv_b  = (const float*)d_in[3];
    const float* io_w    = (const float*)d_in[4];
    const float* io_b    = (const float*)d_in[5];
    const float* mixer_w = (const float*)d_in[6];
    const float* mixer_b = (const float*)d_in[7];
    float* out = (float*)d_out;

    float* s1 = (float*)d_ws;
    float* s2 = s1 + (size_t)NB * TFULL * CH;

    auto wl  = [&](int g) { return conv_w + (size_t)(g - 1) * 3 * 19 * CH; };
    auto bsl = [&](int g) { return conv_b + (size_t)g * CH; };
    auto iwl = [&](int g) { return io_w + (size_t)g * CH * CH; };
    auto ibl = [&](int g) { return io_b + (size_t)g * CH; };
    auto mwl = [&](int g) { return mixer_w + (size_t)g * CH; };

    dim3 blkG(GNT, 1, 1), blk256(256, 1, 1);

    // G_A: layers 0..6 (dil 1..64), halo 254, TILE 480, mains [254,4092), 8x64 blocks
    group2_kernel<0, 7, 480, 254, true><<<dim3(8, NB), blkG, 0, stream>>>(
        input, conv_w0, conv_w, conv_b, io_w, io_b, mixer_w, mixer_b,
        nullptr, s1, out, 254);
    // L7 (dil 128): rows [510,4092) -> s1 -> s2
    single_layer<false><<<dim3(14, NB), blk256, 0, stream>>>(
        input, s1, wl(7), bsl(7), iwl(7), ibl(7), mwl(7), s2, out, 128, 510);
    // L8 (dil 256): rows [1022,4092) -> s2 -> s1
    single_layer<false><<<dim3(12, NB), blk256, 0, stream>>>(
        input, s2, wl(8), bsl(8), iwl(8), ibl(8), mwl(8), s1, out, 256, 1022);
    // G_D': layers 9..16 (dil 1..128), halo 510, TILE 320, mains [1532,4092), 8x64 blocks
    group2_kernel<9, 8, 320, 510, false><<<dim3(8, NB), blkG, 0, stream>>>(
        input, conv_w0, conv_w, conv_b, io_w, io_b, mixer_w, mixer_b,
        s1, s2, out, 1532);
    // L17 (dil 256): rows [2044,4092) -> s2 -> out only
    single_layer<true><<<dim3(8, NB), blk256, 0, stream>>>(
        input, s2, wl(17), bsl(17), nullptr, nullptr, mwl(17), nullptr, out, 256, 2044);
}

// Round 7
// 294.891 us; speedup vs baseline: 7.7714x; 1.0386x over previous
//
#include <hip/hip_runtime.h>

#define TFULL 4092
#define NB    64
#define CH    16
#define OUT_T 2048
#define TOFF  2044
#define GNT   512

__device__ __forceinline__ int wave_first(int v) {
    return __builtin_amdgcn_readfirstlane(v);
}

// ---------------- fused group: SoA LDS planes, 2 rows/thread, wave-uniform
// activity guards (s_load-friendly), clamped-tap garbage rows, per-lane
// guarded writes. Layer loop kept rolled (#pragma unroll 1) for I$.
template<int L0, int NL, int TILE, int HALO, bool FIRSTG>
__global__ __launch_bounds__(GNT, 4) void group3_kernel(
    const float* __restrict__ input,     // (B,T,4)
    const float* __restrict__ conv_w0,   // (3,4,16)
    const float* __restrict__ conv_w,    // (17,3,19,16)
    const float* __restrict__ conv_b,    // (18,16)
    const float* __restrict__ io_w,      // (17,16,16)
    const float* __restrict__ io_b,      // (17,16)
    const float* __restrict__ mixer_w,   // (288)
    const float* __restrict__ mixer_b,   // (1)
    const float* __restrict__ sig_in,    // prev signal (B,T,16); unused if FIRSTG
    float* __restrict__ sig_out,         // group output signal (B,T,16)
    float* __restrict__ out,             // (B,2048)
    int out_start)
{
    constexpr int NROWS = TILE + HALO;
    __shared__ float4 pl0[NROWS], pl1[NROWS], pl2[NROWS], pl3[NROWS], plx[NROWS];

    const int b       = blockIdx.y;
    const int tid     = threadIdx.x;
    const int tile_lo = out_start + blockIdx.x * TILE;
    const int tile_hi = (tile_lo + TILE < TFULL) ? (tile_lo + TILE) : TFULL;
    const int buf_lo  = tile_lo - HALO;
    const int jmax    = tile_hi - buf_lo;     // valid rows [0, jmax)
    const int j0      = NROWS - 1024 + tid;   // may be < 0
    const int j1      = NROWS - 512  + tid;   // in [NROWS-512, NROWS)

    const float4* ib4 = (const float4*)(input + (size_t)b * TFULL * 4);

    for (int j = tid; j < jmax; j += GNT) {
        plx[j] = ib4[buf_lo + j];
        if constexpr (!FIRSTG) {
            const float4* row = (const float4*)(sig_in + ((size_t)b * TFULL + buf_lo + j) * CH);
            pl0[j] = row[0]; pl1[j] = row[1]; pl2[j] = row[2]; pl3[j] = row[3];
        }
    }
    __syncthreads();

    float acc0 = 0.f, acc1 = 0.f;
    float sn0[CH], sn1[CH];
    int lo_off = 0;

    #pragma unroll 1
    for (int i = 0; i < NL; ++i) {
        const int g   = L0 + i;
        const int dil = 1 << (g % 9);
        lo_off += 2 * dil;
        const float* wb   = (FIRSTG && i == 0) ? conv_w0
                                               : conv_w + (size_t)(g - 1) * 3 * 19 * CH;
        const float* bias = conv_b  + (size_t)g * CH;
        const float* iw   = io_w    + (size_t)g * CH * CH;
        const float* ob   = io_b    + (size_t)g * CH;
        const float* mw   = mixer_w + (size_t)g * CH;

        auto do_row = [&](int j, float* sn, float& acc) {
            float h[CH];
            #pragma unroll
            for (int o = 0; o < CH; ++o) h[o] = bias[o];
            float sum;
            if (FIRSTG && i == 0) {
                const float4 x0 = plx[max(j - 2, 0)];
                const float4 x1 = plx[max(j - 1, 0)];
                const float4 x2 = plx[max(j, 0)];
                const float t0[4] = {x0.x, x0.y, x0.z, x0.w};
                const float t1[4] = {x1.x, x1.y, x1.z, x1.w};
                const float t2[4] = {x2.x, x2.y, x2.z, x2.w};
                #pragma unroll
                for (int cc = 0; cc < 4; ++cc) {
                    #pragma unroll
                    for (int o = 0; o < CH; ++o) {
                        h[o] = fmaf(t0[cc], wb[(0 * 4 + cc) * CH + o], h[o]);
                        h[o] = fmaf(t1[cc], wb[(1 * 4 + cc) * CH + o], h[o]);
                        h[o] = fmaf(t2[cc], wb[(2 * 4 + cc) * CH + o], h[o]);
                    }
                }
                sum = x2.x;
            } else {
                sum = 0.f;
                #pragma unroll
                for (int k = 0; k < 3; ++k) {
                    const int jm = max(j - (2 - k) * dil, 0);
                    const float4 s0 = pl0[jm], s1 = pl1[jm], s2 = pl2[jm], s3 = pl3[jm];
                    const float4 x  = plx[jm];
                    if (k == 2)
                        sum = ((s0.x + s0.y) + (s0.z + s0.w)) + ((s1.x + s1.y) + (s1.z + s1.w))
                            + ((s2.x + s2.y) + (s2.z + s2.w)) + ((s3.x + s3.y) + (s3.z + s3.w));
                    const float tv[19] = {s0.x, s0.y, s0.z, s0.w, s1.x, s1.y, s1.z, s1.w,
                                          s2.x, s2.y, s2.z, s2.w, s3.x, s3.y, s3.z, s3.w,
                                          x.y, x.z, x.w};
                    #pragma unroll
                    for (int cc = 0; cc < 19; ++cc) {
                        #pragma unroll
                        for (int o = 0; o < CH; ++o)
                            h[o] = fmaf(tv[cc], wb[(k * 19 + cc) * CH + o], h[o]);
                    }
                }
            }
            #pragma unroll
            for (int o = 0; o < CH; ++o) h[o] = fmaxf(h[o], 0.f);

            const int r = buf_lo + j;
            if (j >= HALO && j < jmax && r >= TOFF) {   // mixer: valid mains only
                float d = 0.f;
                #pragma unroll
                for (int o = 0; o < CH; ++o) d = fmaf(h[o], mw[o], d);
                acc += d;
            }
            const float half = 0.5f * sum;              // io -> next signal
            #pragma unroll
            for (int o = 0; o < CH; ++o) sn[o] = ob[o] + half;
            #pragma unroll
            for (int cc = 0; cc < CH; ++cc) {
                #pragma unroll
                for (int o = 0; o < CH; ++o)
                    sn[o] = fmaf(h[cc], iw[cc * CH + o], sn[o]);
            }
        };

        // wave-uniform activity (readfirstlane -> SGPR branch -> s_load weights)
        const bool w1 = (wave_first(j1) + 63 >= lo_off);
        const bool w0 = (wave_first(j0) + 63 >= lo_off);
        if (w1) do_row(j1, sn1, acc1);
        if (w0) do_row(j0, sn0, acc0);

        if (i != NL - 1) {
            __syncthreads();                            // reads done
            if (w1 && j1 >= lo_off && j1 < jmax) {
                pl0[j1] = make_float4(sn1[0],  sn1[1],  sn1[2],  sn1[3]);
                pl1[j1] = make_float4(sn1[4],  sn1[5],  sn1[6],  sn1[7]);
                pl2[j1] = make_float4(sn1[8],  sn1[9],  sn1[10], sn1[11]);
                pl3[j1] = make_float4(sn1[12], sn1[13], sn1[14], sn1[15]);
            }
            if (w0 && j0 >= lo_off && j0 < jmax) {
                pl0[j0] = make_float4(sn0[0],  sn0[1],  sn0[2],  sn0[3]);
                pl1[j0] = make_float4(sn0[4],  sn0[5],  sn0[6],  sn0[7]);
                pl2[j0] = make_float4(sn0[8],  sn0[9],  sn0[10], sn0[11]);
                pl3[j0] = make_float4(sn0[12], sn0[13], sn0[14], sn0[15]);
            }
            __syncthreads();                            // writes visible
        } else {
            if (j1 >= HALO && j1 < jmax) {              // mains -> global signal
                float* gp = sig_out + ((size_t)b * TFULL + (buf_lo + j1)) * CH;
                *(float4*)(gp + 0)  = make_float4(sn1[0],  sn1[1],  sn1[2],  sn1[3]);
                *(float4*)(gp + 4)  = make_float4(sn1[4],  sn1[5],  sn1[6],  sn1[7]);
                *(float4*)(gp + 8)  = make_float4(sn1[8],  sn1[9],  sn1[10], sn1[11]);
                *(float4*)(gp + 12) = make_float4(sn1[12], sn1[13], sn1[14], sn1[15]);
            }
            if (j0 >= HALO && j0 < jmax) {
                float* gp = sig_out + ((size_t)b * TFULL + (buf_lo + j0)) * CH;
                *(float4*)(gp + 0)  = make_float4(sn0[0],  sn0[1],  sn0[2],  sn0[3]);
                *(float4*)(gp + 4)  = make_float4(sn0[4],  sn0[5],  sn0[6],  sn0[7]);
                *(float4*)(gp + 8)  = make_float4(sn0[8],  sn0[9],  sn0[10], sn0[11]);
                *(float4*)(gp + 12) = make_float4(sn0[12], sn0[13], sn0[14], sn0[15]);
            }
        }
    }

    if (j0 >= HALO && j0 < jmax) {
        const int r = buf_lo + j0;
        if (r >= TOFF) {
            const size_t oi = (size_t)b * OUT_T + (r - TOFF);
            if constexpr (FIRSTG) out[oi] = mixer_b[0] + acc0; else out[oi] += acc0;
        }
    }
    if (j1 >= HALO && j1 < jmax) {
        const int r = buf_lo + j1;
        if (r >= TOFF) {
            const size_t oi = (size_t)b * OUT_T + (r - TOFF);
            if constexpr (FIRSTG) out[oi] = mixer_b[0] + acc1; else out[oi] += acc1;
        }
    }
}

// ---------------- unfused single layer (big dilation, zero halo), de-diverged ----------------
template<bool LASTL>
__global__ __launch_bounds__(256, 4) void single_layer(
    const float* __restrict__ input,    // (B,T,4)
    const float* __restrict__ sig_in,   // (B,T,16)
    const float* __restrict__ w,        // (3,19,16)
    const float* __restrict__ bias,     // (16)
    const float* __restrict__ iw,       // (16,16)   unused if LASTL
    const float* __restrict__ iob,      // (16)      unused if LASTL
    const float* __restrict__ mw,       // (16)
    float* __restrict__ sig_out,        // (B,T,16)  unused if LASTL
    float* __restrict__ out,            // (B,2048)
    int dil, int t0)
{
    const int b    = blockIdx.y;
    const int traw = t0 + blockIdx.x * 256 + threadIdx.x;
    const int t    = (traw < TFULL) ? traw : (TFULL - 1);   // clamp, guard stores
    const float* ib = input  + (size_t)b * TFULL * 4;
    const float* sb = sig_in + (size_t)b * TFULL * CH;

    const int tt0 = t - 2 * dil, tt1 = t - dil;
    const float4* sp0 = (const float4*)(sb + (size_t)tt0 * CH);
    const float4* sp1 = (const float4*)(sb + (size_t)tt1 * CH);
    const float4* sp2 = (const float4*)(sb + (size_t)t   * CH);
    const float4 a0 = sp0[0], a1 = sp0[1], a2 = sp0[2], a3 = sp0[3];
    const float4 b0 = sp1[0], b1 = sp1[1], b2 = sp1[2], b3 = sp1[3];
    const float4 c0 = sp2[0], c1 = sp2[1], c2 = sp2[2], c3 = sp2[3];
    const float4 x0 = *(const float4*)(ib + (size_t)tt0 * 4);
    const float4 x1 = *(const float4*)(ib + (size_t)tt1 * 4);
    const float4 x2 = *(const float4*)(ib + (size_t)t   * 4);

    float h[CH];
    #pragma unroll
    for (int o = 0; o < CH; ++o) h[o] = bias[o];

    const float t0v[19] = {a0.x,a0.y,a0.z,a0.w, a1.x,a1.y,a1.z,a1.w,
                           a2.x,a2.y,a2.z,a2.w, a3.x,a3.y,a3.z,a3.w,
                           x0.y,x0.z,x0.w};
    const float t1v[19] = {b0.x,b0.y,b0.z,b0.w, b1.x,b1.y,b1.z,b1.w,
                           b2.x,b2.y,b2.z,b2.w, b3.x,b3.y,b3.z,b3.w,
                           x1.y,x1.z,x1.w};
    const float t2v[19] = {c0.x,c0.y,c0.z,c0.w, c1.x,c1.y,c1.z,c1.w,
                           c2.x,c2.y,c2.z,c2.w, c3.x,c3.y,c3.z,c3.w,
                           x2.y,x2.z,x2.w};
    #pragma unroll
    for (int cc = 0; cc < 19; ++cc) {
        #pragma unroll
        for (int o = 0; o < CH; ++o) {
            h[o] = fmaf(t0v[cc], w[(0 * 19 + cc) * CH + o], h[o]);
            h[o] = fmaf(t1v[cc], w[(1 * 19 + cc) * CH + o], h[o]);
            h[o] = fmaf(t2v[cc], w[(2 * 19 + cc) * CH + o], h[o]);
        }
    }
    #pragma unroll
    for (int o = 0; o < CH; ++o) h[o] = fmaxf(h[o], 0.f);

    if (traw < TFULL && traw >= TOFF) {
        float m = 0.f;
        #pragma unroll
        for (int o = 0; o < CH; ++o) m = fmaf(h[o], mw[o], m);
        out[(size_t)b * OUT_T + (traw - TOFF)] += m;
    }

    if constexpr (!LASTL) {
        const float sum_t = ((c0.x + c0.y) + (c0.z + c0.w)) + ((c1.x + c1.y) + (c1.z + c1.w))
                          + ((c2.x + c2.y) + (c2.z + c2.w)) + ((c3.x + c3.y) + (c3.z + c3.w));
        float sn[CH];
        const float half = 0.5f * sum_t;
        #pragma unroll
        for (int o = 0; o < CH; ++o) sn[o] = iob[o] + half;
        #pragma unroll
        for (int cc = 0; cc < CH; ++cc) {
            #pragma unroll
            for (int o = 0; o < CH; ++o)
                sn[o] = fmaf(h[cc], iw[cc * CH + o], sn[o]);
        }
        if (traw < TFULL) {
            float* gp = sig_out + ((size_t)b * TFULL + traw) * CH;
            *(float4*)(gp + 0)  = make_float4(sn[0],  sn[1],  sn[2],  sn[3]);
            *(float4*)(gp + 4)  = make_float4(sn[4],  sn[5],  sn[6],  sn[7]);
            *(float4*)(gp + 8)  = make_float4(sn[8],  sn[9],  sn[10], sn[11]);
            *(float4*)(gp + 12) = make_float4(sn[12], sn[13], sn[14], sn[15]);
        }
    }
}

extern "C" void kernel_launch(void* const* d_in, const int* in_sizes, int n_in,
                              void* d_out, int out_size, void* d_ws, size_t ws_size,
                              hipStream_t stream) {
    const float* input   = (const float*)d_in[0];
    const float* conv_w0 = (const float*)d_in[1];
    const float* conv_w  = (const float*)d_in[2];
    const float* conv_b  = (const float*)d_in[3];
    const float* io_w    = (const float*)d_in[4];
    const float* io_b    = (const float*)d_in[5];
    const float* mixer_w = (const float*)d_in[6];
    const float* mixer_b = (const float*)d_in[7];
    float* out = (float*)d_out;

    float* s1 = (float*)d_ws;
    float* s2 = s1 + (size_t)NB * TFULL * CH;

    auto wl  = [&](int g) { return conv_w + (size_t)(g - 1) * 3 * 19 * CH; };
    auto bsl = [&](int g) { return conv_b + (size_t)g * CH; };
    auto iwl = [&](int g) { return io_w + (size_t)g * CH * CH; };
    auto ibl = [&](int g) { return io_b + (size_t)g * CH; };
    auto mwl = [&](int g) { return mixer_w + (size_t)g * CH; };

    dim3 blkG(GNT, 1, 1), blk256(256, 1, 1);

    // G_A: layers 0..6 (dil 1..64), halo 254, TILE 480, mains [254,4092), LDS 58.7KB
    group3_kernel<0, 7, 480, 254, true><<<dim3(8, NB), blkG, 0, stream>>>(
        input, conv_w0, conv_w, conv_b, io_w, io_b, mixer_w, mixer_b,
        nullptr, s1, out, 254);
    // L7 (dil 128): t in [510,4092) ; s1 -> s2
    single_layer<false><<<dim3(14, NB), blk256, 0, stream>>>(
        input, s1, wl(7), bsl(7), iwl(7), ibl(7), mwl(7), s2, out, 128, 510);
    // L8 (dil 256): t in [1022,4092) ; s2 -> s1
    single_layer<false><<<dim3(12, NB), blk256, 0, stream>>>(
        input, s2, wl(8), bsl(8), iwl(8), ibl(8), mwl(8), s1, out, 256, 1022);
    // G_D: layers 9..15 (dil 1..64), halo 254, TILE 352, mains [1276,4092), LDS 48.5KB
    group3_kernel<9, 7, 352, 254, false><<<dim3(8, NB), blkG, 0, stream>>>(
        input, conv_w0, conv_w, conv_b, io_w, io_b, mixer_w, mixer_b,
        s1, s2, out, 1276);
    // L16 (dil 128): t in [1532,4092) ; s2 -> s1
    single_layer<false><<<dim3(10, NB), blk256, 0, stream>>>(
        input, s2, wl(16), bsl(16), iwl(16), ibl(16), mwl(16), s1, out, 128, 1532);
    // L17 (dil 256): t in [2044,4092) ; s1 -> out only
    single_layer<true><<<dim3(8, NB), blk256, 0, stream>>>(
        input, s1, wl(17), bsl(17), nullptr, nullptr, mwl(17), nullptr, out, 256, 2044);
}